// Round 1
// baseline (734.538 us; speedup 1.0000x reference)
//
#include <hip/hip_runtime.h>
#include <math.h>

#define BB 32
#define SS 4096
#define HH 1024

typedef float fvec4 __attribute__((ext_vector_type(4)));

// ---------------------------------------------------------------------------
// Kernel A: v[b,h] = sum_k hidden[b,k] * W[k,h]
// grid (HH/64, BB), block 256 = 64 h-lanes x 4 k-slices, LDS tree reduce.
// No atomics, no memset: v fully overwritten each launch (ws-poison safe).
// Per k, a wave reads 256 B contiguous of W (L2-served after first b).
// ---------------------------------------------------------------------------
__global__ __launch_bounds__(256) void compute_v_kernel(
        const float* __restrict__ hidden,
        const float* __restrict__ W,
        float* __restrict__ v) {
    const int b = blockIdx.y;
    const int hl = threadIdx.x & 63;
    const int h = blockIdx.x * 64 + hl;
    const int slice = threadIdx.x >> 6;          // 0..3
    const int k0 = slice * 256;
    const float* __restrict__ hb = hidden + b * HH + k0;   // wave-uniform
    const float* __restrict__ Wp = W + (size_t)k0 * HH + h;
    float a0 = 0.f, a1 = 0.f, a2 = 0.f, a3 = 0.f;
#pragma unroll 8
    for (int k = 0; k < 256; k += 4) {
        a0 = fmaf(hb[k + 0], Wp[(size_t)(k + 0) * HH], a0);
        a1 = fmaf(hb[k + 1], Wp[(size_t)(k + 1) * HH], a1);
        a2 = fmaf(hb[k + 2], Wp[(size_t)(k + 2) * HH], a2);
        a3 = fmaf(hb[k + 3], Wp[(size_t)(k + 3) * HH], a3);
    }
    __shared__ float red[256];
    red[threadIdx.x] = (a0 + a1) + (a2 + a3);
    __syncthreads();
    if (threadIdx.x < 64)
        v[b * HH + h] =
            (red[hl] + red[64 + hl]) + (red[128 + hl] + red[192 + hl]);
}

// ---------------------------------------------------------------------------
// Kernel B: scores[b,s] = dot(enc[b,s,:], v[b,:]).
// Lane-per-row: each lane owns one full s-row (4 KB). v[b] staged in LDS,
// read with same-address broadcast (conflict-free). No shuffles; accumulator
// stays in-lane; store is 256 B contiguous per wave. All 256 row loads fit
// the 13-bit immediate offset (k*16 <= 4080), so the hot loop is pure
// global_load_dwordx4 offset:N + ds_read_b128 + v_fma.
// grid (SS/256, BB) = 512 blocks, block 256.
// ---------------------------------------------------------------------------
__global__ __launch_bounds__(256) void compute_scores_kernel(
        const float* __restrict__ enc,
        const float* __restrict__ v,
        float* __restrict__ scores) {
    const int b = blockIdx.y;
    const int s = blockIdx.x * 256 + threadIdx.x;

    __shared__ fvec4 vs[HH / 4];                 // 4 KiB
    vs[threadIdx.x] = ((const fvec4*)(v + (size_t)b * HH))[threadIdx.x];
    __syncthreads();

    const fvec4* __restrict__ e =
        (const fvec4*)(enc + ((size_t)b * SS + s) * HH);

    fvec4 acc0 = {0.f, 0.f, 0.f, 0.f};
    fvec4 acc1 = {0.f, 0.f, 0.f, 0.f};
#pragma unroll 2
    for (int k = 0; k < HH / 4; k += 8) {
        fvec4 e0 = e[k + 0], e1 = e[k + 1], e2 = e[k + 2], e3 = e[k + 3];
        fvec4 e4 = e[k + 4], e5 = e[k + 5], e6 = e[k + 6], e7 = e[k + 7];
        acc0 += e0 * vs[k + 0];
        acc1 += e1 * vs[k + 1];
        acc0 += e2 * vs[k + 2];
        acc1 += e3 * vs[k + 3];
        acc0 += e4 * vs[k + 4];
        acc1 += e5 * vs[k + 5];
        acc0 += e6 * vs[k + 6];
        acc1 += e7 * vs[k + 7];
    }
    const fvec4 t = acc0 + acc1;
    scores[(size_t)b * SS + s] = (t.x + t.y) + (t.z + t.w);
}

// ---------------------------------------------------------------------------
// Kernel C: in-place softmax over S per batch row. One block per b,
// 1024 threads, 4 elements each. (bias logit constant cancels in softmax.)
// ---------------------------------------------------------------------------
__global__ __launch_bounds__(1024) void softmax_kernel(float* __restrict__ scores) {
    const int b = blockIdx.x;
    float* __restrict__ row = scores + (size_t)b * SS;
    const int tid = threadIdx.x;
    const int lane = tid & 63;
    const int wave = tid >> 6;   // 16 waves

    __shared__ float red_max[16];
    __shared__ float red_sum[16];

    float vals[4];
    float m = -INFINITY;
#pragma unroll
    for (int i = 0; i < 4; ++i) {
        vals[i] = row[i * 1024 + tid];
        m = fmaxf(m, vals[i]);
    }
#pragma unroll
    for (int off = 32; off > 0; off >>= 1)
        m = fmaxf(m, __shfl_xor(m, off, 64));
    if (lane == 0) red_max[wave] = m;
    __syncthreads();
#pragma unroll
    for (int i = 0; i < 16; ++i) m = fmaxf(m, red_max[i]);

    float sum = 0.f;
#pragma unroll
    for (int i = 0; i < 4; ++i) {
        vals[i] = __expf(vals[i] - m);
        sum += vals[i];
    }
#pragma unroll
    for (int off = 32; off > 0; off >>= 1)
        sum += __shfl_xor(sum, off, 64);
    if (lane == 0) red_sum[wave] = sum;
    __syncthreads();
    sum = 0.f;
#pragma unroll
    for (int i = 0; i < 16; ++i) sum += red_sum[i];

    const float inv = 1.f / sum;
#pragma unroll
    for (int i = 0; i < 4; ++i)
        row[i * 1024 + tid] = vals[i] * inv;
}

extern "C" void kernel_launch(void* const* d_in, const int* in_sizes, int n_in,
                              void* d_out, int out_size, void* d_ws, size_t ws_size,
                              hipStream_t stream) {
    const float* hidden = (const float*)d_in[0];   // [B,1,H]
    const float* enc    = (const float*)d_in[1];   // [B,S,H]
    const float* W      = (const float*)d_in[2];   // [H,H]
    // d_in[3] = bias[H]: per-b constant logit, cancels exactly in softmax.
    float* out = (float*)d_out;                    // [B,S] fp32
    float* v   = (float*)d_ws;                     // [B,H] scratch (128 KiB)

    compute_v_kernel<<<dim3(HH / 64, BB), 256, 0, stream>>>(hidden, W, v);
    compute_scores_kernel<<<dim3(SS / 256, BB), 256, 0, stream>>>(enc, v, out);
    softmax_kernel<<<BB, 1024, 0, stream>>>(out);
}

// Round 2
// 671.986 us; speedup vs baseline: 1.0931x; 1.0931x over previous
//
#include <hip/hip_runtime.h>
#include <math.h>

#define BB 32
#define SS 4096
#define HH 1024

typedef float fvec4 __attribute__((ext_vector_type(4)));

// ---------------------------------------------------------------------------
// Kernel A: v[b,h] = sum_k hidden[b,k] * W[k,h]
// grid (HH/64, BB), block 256 = 64 h-lanes x 4 k-slices, LDS tree reduce.
// No atomics, no memset: v fully overwritten each launch (ws-poison safe).
// Per k, a wave reads 256 B contiguous of W (L2-served after first b).
// ---------------------------------------------------------------------------
__global__ __launch_bounds__(256) void compute_v_kernel(
        const float* __restrict__ hidden,
        const float* __restrict__ W,
        float* __restrict__ v) {
    const int b = blockIdx.y;
    const int hl = threadIdx.x & 63;
    const int h = blockIdx.x * 64 + hl;
    const int slice = threadIdx.x >> 6;          // 0..3
    const int k0 = slice * 256;
    const float* __restrict__ hb = hidden + b * HH + k0;   // wave-uniform
    const float* __restrict__ Wp = W + (size_t)k0 * HH + h;
    float a0 = 0.f, a1 = 0.f, a2 = 0.f, a3 = 0.f;
#pragma unroll 8
    for (int k = 0; k < 256; k += 4) {
        a0 = fmaf(hb[k + 0], Wp[(size_t)(k + 0) * HH], a0);
        a1 = fmaf(hb[k + 1], Wp[(size_t)(k + 1) * HH], a1);
        a2 = fmaf(hb[k + 2], Wp[(size_t)(k + 2) * HH], a2);
        a3 = fmaf(hb[k + 3], Wp[(size_t)(k + 3) * HH], a3);
    }
    __shared__ float red[256];
    red[threadIdx.x] = (a0 + a1) + (a2 + a3);
    __syncthreads();
    if (threadIdx.x < 64)
        v[b * HH + h] =
            (red[hl] + red[64 + hl]) + (red[128 + hl] + red[192 + hl]);
}

// ---------------------------------------------------------------------------
// Kernel B: scores[b,s] = dot(enc[b,s,:], v[b,:]).
// Proven round-0 load structure: one wave handles 4 consecutive s rows,
// each row read as 4x 1KB-coalesced fvec4 wave-loads (16 independent loads
// in flight). enc is streamed non-temporally (zero reuse; each 128B line is
// fully consumed by a single instruction) so v/W stay warm in L2.
// Reduction tail: interleaved pairwise merge — 10 shuffles instead of 24;
// after xor1+xor2 merges, lane l holds row (l&3); xor4..32 finish the sum;
// lanes 0..3 store 4B each (coalesced 16B segment).
// Grid (SS/16, BB), block 256 (4 waves -> 16 s per block).
// ---------------------------------------------------------------------------
__global__ __launch_bounds__(256) void compute_scores_kernel(
        const float* __restrict__ enc,
        const float* __restrict__ v,
        float* __restrict__ scores) {
    const int b = blockIdx.y;
    const int wave = threadIdx.x >> 6;
    const int lane = threadIdx.x & 63;
    const int s0 = (blockIdx.x * 4 + wave) * 4;

    const fvec4* __restrict__ v4 = (const fvec4*)(v + b * HH);
    const fvec4 w0 = v4[lane];
    const fvec4 w1 = v4[64 + lane];
    const fvec4 w2 = v4[128 + lane];
    const fvec4 w3 = v4[192 + lane];

    const fvec4* __restrict__ e4 =
        (const fvec4*)(enc + ((size_t)b * SS + s0) * HH);

    float acc[4];
#pragma unroll
    for (int j = 0; j < 4; ++j) {
        const fvec4* __restrict__ p = e4 + (size_t)j * 256;
        fvec4 e0 = __builtin_nontemporal_load(&p[lane]);
        fvec4 e1 = __builtin_nontemporal_load(&p[64 + lane]);
        fvec4 e2 = __builtin_nontemporal_load(&p[128 + lane]);
        fvec4 e3 = __builtin_nontemporal_load(&p[192 + lane]);
        fvec4 t = e0 * w0 + e1 * w1 + e2 * w2 + e3 * w3;
        acc[j] = t.x + t.y + t.z + t.w;
    }

    // Level 1 (xor 1): even lanes keep rows {0,2}, odd lanes rows {1,3}.
    float t0 = acc[0] + __shfl_xor(acc[0], 1, 64);
    float t1 = acc[1] + __shfl_xor(acc[1], 1, 64);
    float t2 = acc[2] + __shfl_xor(acc[2], 1, 64);
    float t3 = acc[3] + __shfl_xor(acc[3], 1, 64);
    float r01 = (lane & 1) ? t1 : t0;
    float r23 = (lane & 1) ? t3 : t2;
    // Level 2 (xor 2): lane l now holds row (l&3), summed over its 4-group.
    float u01 = r01 + __shfl_xor(r01, 2, 64);
    float u23 = r23 + __shfl_xor(r23, 2, 64);
    float r = (lane & 2) ? u23 : u01;
    // Levels 3..6: finish across the wave (same row on lanes ≡ l&3 mod 4).
    r += __shfl_xor(r, 4, 64);
    r += __shfl_xor(r, 8, 64);
    r += __shfl_xor(r, 16, 64);
    r += __shfl_xor(r, 32, 64);

    if (lane < 4)
        scores[(size_t)b * SS + s0 + lane] = r;
}

// ---------------------------------------------------------------------------
// Kernel C: in-place softmax over S per batch row. One block per b,
// 1024 threads, 4 elements each. (bias logit constant cancels in softmax.)
// ---------------------------------------------------------------------------
__global__ __launch_bounds__(1024) void softmax_kernel(float* __restrict__ scores) {
    const int b = blockIdx.x;
    float* __restrict__ row = scores + (size_t)b * SS;
    const int tid = threadIdx.x;
    const int lane = tid & 63;
    const int wave = tid >> 6;   // 16 waves

    __shared__ float red_max[16];
    __shared__ float red_sum[16];

    float vals[4];
    float m = -INFINITY;
#pragma unroll
    for (int i = 0; i < 4; ++i) {
        vals[i] = row[i * 1024 + tid];
        m = fmaxf(m, vals[i]);
    }
#pragma unroll
    for (int off = 32; off > 0; off >>= 1)
        m = fmaxf(m, __shfl_xor(m, off, 64));
    if (lane == 0) red_max[wave] = m;
    __syncthreads();
#pragma unroll
    for (int i = 0; i < 16; ++i) m = fmaxf(m, red_max[i]);

    float sum = 0.f;
#pragma unroll
    for (int i = 0; i < 4; ++i) {
        vals[i] = __expf(vals[i] - m);
        sum += vals[i];
    }
#pragma unroll
    for (int off = 32; off > 0; off >>= 1)
        sum += __shfl_xor(sum, off, 64);
    if (lane == 0) red_sum[wave] = sum;
    __syncthreads();
    sum = 0.f;
#pragma unroll
    for (int i = 0; i < 16; ++i) sum += red_sum[i];

    const float inv = 1.f / sum;
#pragma unroll
    for (int i = 0; i < 4; ++i)
        row[i * 1024 + tid] = vals[i] * inv;
}

extern "C" void kernel_launch(void* const* d_in, const int* in_sizes, int n_in,
                              void* d_out, int out_size, void* d_ws, size_t ws_size,
                              hipStream_t stream) {
    const float* hidden = (const float*)d_in[0];   // [B,1,H]
    const float* enc    = (const float*)d_in[1];   // [B,S,H]
    const float* W      = (const float*)d_in[2];   // [H,H]
    // d_in[3] = bias[H]: per-b constant logit, cancels exactly in softmax.
    float* out = (float*)d_out;                    // [B,S] fp32
    float* v   = (float*)d_ws;                     // [B,H] scratch (128 KiB)

    compute_v_kernel<<<dim3(HH / 64, BB), 256, 0, stream>>>(hidden, W, v);
    compute_scores_kernel<<<dim3(SS / 16, BB), 256, 0, stream>>>(enc, v, out);
    softmax_kernel<<<BB, 1024, 0, stream>>>(out);
}